// Round 10
// baseline (705.160 us; speedup 1.0000x reference)
//
#include <hip/hip_runtime.h>
#include <hip/hip_bf16.h>

// Problem constants (match reference)
#define NN 100000
#define NE 500000
#define RELS 4
#define NCLS 16
#define SCAN_B 1024
#define NCHUNK ((NN + SCAN_B - 1) / SCAN_B)   // 98

typedef __attribute__((ext_vector_type(8))) short s16x8;
typedef __attribute__((ext_vector_type(4))) float f32x4;

__device__ __forceinline__ float bf2f(unsigned short u) {
    return __uint_as_float(((unsigned int)u) << 16);
}
__device__ __forceinline__ unsigned short f2bfbits(float f) {
    __hip_bfloat16 h = __float2bfloat16(f);
    return *reinterpret_cast<unsigned short*>(&h);
}

// ---------------- CSR build ----------------

__global__ void hist_kernel(const int* __restrict__ e0, const int* __restrict__ e1,
                            const int* __restrict__ e2, const int* __restrict__ e3,
                            int* __restrict__ counts) {
    int i = blockIdx.x * 256 + threadIdx.x;
    int rel = blockIdx.y;
    if (i >= NE) return;
    const int* ep = (rel == 0) ? e0 : (rel == 1) ? e1 : (rel == 2) ? e2 : e3;
    int d = ep[NE + i];              // dst row
    atomicAdd(&counts[rel * NN + d], 1);
}

__global__ void scanA_kernel(const int* __restrict__ counts, int* __restrict__ bsums) {
    int rel = blockIdx.y, chunk = blockIdx.x;
    int i = chunk * SCAN_B + threadIdx.x;
    __shared__ int s[SCAN_B];
    int v = (i < NN) ? counts[rel * NN + i] : 0;
    s[threadIdx.x] = v;
    __syncthreads();
    for (int off = SCAN_B / 2; off > 0; off >>= 1) {
        if (threadIdx.x < off) s[threadIdx.x] += s[threadIdx.x + off];
        __syncthreads();
    }
    if (threadIdx.x == 0) bsums[rel * 128 + chunk] = s[0];
}

__global__ void scanB_kernel(int* __restrict__ bsums, int* __restrict__ rowptr) {
    int r = threadIdx.x;
    if (r < RELS) {
        int acc = 0;
        for (int c = 0; c < NCHUNK; ++c) {
            int v = bsums[r * 128 + c];
            bsums[r * 128 + c] = acc;
            acc += v;
        }
        rowptr[r * (NN + 1) + NN] = acc;   // == NE
    }
}

__global__ void scanC_kernel(const int* __restrict__ counts, const int* __restrict__ bsums,
                             int* __restrict__ rowptr) {
    int rel = blockIdx.y, chunk = blockIdx.x;
    int i = chunk * SCAN_B + threadIdx.x;
    __shared__ int s[SCAN_B];
    int v = (i < NN) ? counts[rel * NN + i] : 0;
    s[threadIdx.x] = v;
    __syncthreads();
    for (int off = 1; off < SCAN_B; off <<= 1) {
        int add = (threadIdx.x >= (unsigned)off) ? s[threadIdx.x - off] : 0;
        __syncthreads();
        s[threadIdx.x] += add;
        __syncthreads();
    }
    if (i < NN)
        rowptr[rel * (NN + 1) + i] = bsums[rel * 128 + chunk] + s[threadIdx.x] - v;
}

__global__ void fill_kernel(const int* __restrict__ e0, const int* __restrict__ e1,
                            const int* __restrict__ e2, const int* __restrict__ e3,
                            const int* __restrict__ rowptr, int* __restrict__ cursor,
                            int* __restrict__ col) {
    int i = blockIdx.x * 256 + threadIdx.x;
    int rel = blockIdx.y;
    if (i >= NE) return;
    const int* ep = (rel == 0) ? e0 : (rel == 1) ? e1 : (rel == 2) ? e2 : e3;
    int src = ep[i];
    int dst = ep[NE + i];
    int p = atomicAdd(&cursor[rel * NN + dst], 1);
    col[rel * NE + rowptr[rel * (NN + 1) + dst] + p] = src;
}

// ---------------- weight conversion ----------------
// BT[l][n][k] (bf16, k contiguous, n = output col 0..639):
//   n<512  -> W_nbr[l][n>>7][k][n&127]
//   n>=512 -> sum_r W_root[l][r][k][n-512]
// bsum[l][c] = sum_r b_nbr[l][r][c]  (fp32)

__global__ void wconv_kernel(const float* __restrict__ Wn, const float* __restrict__ Wr,
                             const float* __restrict__ bn, __hip_bfloat16* __restrict__ BT,
                             float* __restrict__ bsum) {
    int idx = blockIdx.x * 256 + threadIdx.x;
    if (idx < 2 * 640 * 128) {
        int l = (idx >= 640 * 128) ? 1 : 0;
        int rem = idx - l * 640 * 128;
        int n = rem >> 7;
        int k = rem & 127;
        float v;
        if (n < 512) {
            v = Wn[(((size_t)l * RELS + (n >> 7)) * 128 + k) * 128 + (n & 127)];
        } else {
            v = 0.f;
            for (int r = 0; r < RELS; ++r)
                v += Wr[(((size_t)l * RELS + r) * 128 + k) * 128 + (n - 512)];
        }
        BT[((size_t)l * 640 + n) * 128 + k] = __float2bfloat16(v);
    } else if (idx < 2 * 640 * 128 + 256) {
        int i = idx - 2 * 640 * 128;
        int l = i >> 7, c = i & 127;
        float a = 0.f;
        for (int r = 0; r < RELS; ++r) a += bn[((size_t)l * RELS + r) * 128 + c];
        bsum[i] = a;
    }
}

// ---------------- x -> bf16 compact h0 [N,128] ----------------

__global__ void x2bf_kernel(const float* __restrict__ x, __hip_bfloat16* __restrict__ h) {
    int idx8 = blockIdx.x * 256 + threadIdx.x;    // one thread = 8 elements
    int node = idx8 >> 4;
    int c = (idx8 & 15) * 8;
    if (node >= NN) return;
    float4 f0 = *(const float4*)(x + (size_t)node * 128 + c);
    float4 f1 = *(const float4*)(x + (size_t)node * 128 + c + 4);
    uint4 o;
    o.x = f2bfbits(f0.x) | ((unsigned)f2bfbits(f0.y) << 16);
    o.y = f2bfbits(f0.z) | ((unsigned)f2bfbits(f0.w) << 16);
    o.z = f2bfbits(f1.x) | ((unsigned)f2bfbits(f1.y) << 16);
    o.w = f2bfbits(f1.z) | ((unsigned)f2bfbits(f1.w) << 16);
    *(uint4*)(h + (size_t)node * 128 + c) = o;
}

// ---------------- dense GEMM: [Y | S] = h @ BTl^T, split by col-tile ----------------
// grid = (row_blocks, 5). Each block: BM=64 rows x one 128-col tile. LDS 32 KB
// (A 16K + B 16K; C staged into dead B) -> 5 blocks/CU. K=128 in 2 chunks of 64.
// 4 waves (2x2), wave 32x64 via 2x4 mfma_f32_16x16x32_bf16. Raw output (no
// bias/relu) -- gather_finish applies mean+bias+relu.

__global__ __launch_bounds__(256, 5) void dense_gemm_kernel(
    const __hip_bfloat16* __restrict__ hin, __hip_bfloat16* __restrict__ Y,
    __hip_bfloat16* __restrict__ hS, const __hip_bfloat16* __restrict__ BTl, int M) {
    __shared__ uint4 smem4[2048];            // 32 KB: A 16K | B 16K (C reuses B)
    char* AsB = (char*)smem4;                // [64 rows][128 k] bf16, swizzled
    char* BsB = (char*)smem4 + 16384;        // [128 n ][64 k] per chunk
    int t = threadIdx.x;
    int l = t & 63;
    int wave = t >> 6;
    int wm = wave >> 1, wn = wave & 1;
    int row0 = blockIdx.x * 64;
    int ct = blockIdx.y;                     // col-tile 0..4

    int bn_ = t >> 1;                // B stage: n row 0..127
    int bj = t & 1;                  // B stage: 32-elem half
    int lrow = l & 15;               // MFMA fragment row/col within 16
    int lkg = l >> 4;                // MFMA k-group 0..3

    // ---- stage A tile: 64 rows x 256B; thread owns row t>>2, 64B part t&3 ----
    {
        int row = t >> 2, part = t & 3;
        int grow = row0 + row;
        uint4 v[4] = {};
        if (grow < M) {
#pragma unroll
            for (int j = 0; j < 4; ++j)
                v[j] = *(const uint4*)(hin + (size_t)grow * 128 + part * 32 + j * 8);
        }
#pragma unroll
        for (int j = 0; j < 4; ++j) {
            int q = part * 4 + j;
            *(uint4*)(AsB + row * 256 + ((q ^ (row & 7)) << 4)) = v[j];
        }
    }

    uint4 breg[4];
    {
        const __hip_bfloat16* gb = BTl + ((size_t)(ct * 128 + bn_)) * 128 + bj * 32;
#pragma unroll
        for (int j = 0; j < 4; ++j) breg[j] = *(const uint4*)(gb + j * 8);
    }
    __syncthreads();                 // A tile + (B not yet in LDS)

    f32x4 acc[2][4];
#pragma unroll
    for (int i = 0; i < 2; ++i)
#pragma unroll
        for (int j = 0; j < 4; ++j) acc[i][j] = (f32x4){0.f, 0.f, 0.f, 0.f};

    for (int c = 0; c < 2; ++c) {
        // write staged B chunk -> LDS
#pragma unroll
        for (int j = 0; j < 4; ++j) {
            int q = bj * 4 + j;
            *(uint4*)(BsB + bn_ * 128 + ((q ^ (bn_ & 7)) << 4)) = breg[j];
        }
        if (c == 0) {                // prefetch chunk 1 under MFMA
            const __hip_bfloat16* gb =
                BTl + ((size_t)(ct * 128 + bn_)) * 128 + 64 + bj * 32;
#pragma unroll
            for (int j = 0; j < 4; ++j) breg[j] = *(const uint4*)(gb + j * 8);
        }
        __syncthreads();
#pragma unroll
        for (int kk = 0; kk < 2; ++kk) {
            s16x8 af[2], bfr[4];
            int qa = c * 8 + kk * 4 + lkg;
            int qb = kk * 4 + lkg;
#pragma unroll
            for (int mi = 0; mi < 2; ++mi) {
                int row = wm * 32 + mi * 16 + lrow;
                af[mi] = *(const s16x8*)(AsB + row * 256 + ((qa ^ (row & 7)) << 4));
            }
#pragma unroll
            for (int ni = 0; ni < 4; ++ni) {
                int nrow = wn * 64 + ni * 16 + lrow;
                bfr[ni] = *(const s16x8*)(BsB + nrow * 128 + ((qb ^ (nrow & 7)) << 4));
            }
#pragma unroll
            for (int mi = 0; mi < 2; ++mi)
#pragma unroll
                for (int ni = 0; ni < 4; ++ni)
                    acc[mi][ni] = __builtin_amdgcn_mfma_f32_16x16x32_bf16(
                        af[mi], bfr[ni], acc[mi][ni], 0, 0, 0);
        }
        __syncthreads();             // BsB reads done (before rewrite / C staging)
    }

    // ---- stage bf16 C tile into dead B region, then contiguous stores ----
    {
        int cr = l >> 4;
        int cc = l & 15;
#pragma unroll
        for (int ni = 0; ni < 4; ++ni) {
            int colg = wn * 64 + ni * 16 + cc;
            int q = colg >> 3;
            int cb = (colg & 7) * 2;
#pragma unroll
            for (int mi = 0; mi < 2; ++mi) {
#pragma unroll
                for (int r = 0; r < 4; ++r) {
                    int row = wm * 32 + mi * 16 + cr * 4 + r;
                    int byte = row * 256 + ((q ^ (row & 15)) << 4) + cb;
                    *(unsigned short*)(BsB + byte) = f2bfbits(acc[mi][ni][r]);
                }
            }
        }
    }
    __syncthreads();
    {
        int row = t >> 2;
        int part = t & 3;
        int grow = row0 + row;
        if (grow < M) {
            __hip_bfloat16* dst = (ct < 4)
                ? (Y + (size_t)grow * 512 + ct * 128 + part * 32)
                : (hS + (size_t)grow * 128 + part * 32);
#pragma unroll
            for (int j = 0; j < 4; ++j) {
                int q = part * 4 + j;
                uint4 v = *(const uint4*)(BsB + row * 256 + ((q ^ (row & 15)) << 4));
                *(uint4*)(dst + j * 8) = v;
            }
        }
    }
}

// ---------------- gather-finish: h = relu(0.25*(sum_r mean_r(Y_r) + S + bias)) ----------------
// In-place over hS. 8 lanes x 32B per node (2x16B loads per edge-visit),
// 32 nodes per 256-thread block -> 8 node-chains per wave, unroll-2 edges
// -> 4 loads in flight per lane. No LDS, no barriers.

__global__ void gather_finish_kernel(const int* __restrict__ rowptr,
                                     const int* __restrict__ col,
                                     const __hip_bfloat16* __restrict__ Y,
                                     __hip_bfloat16* __restrict__ hS,
                                     const float* __restrict__ bsum) {
    int t = threadIdx.x;
    int node = blockIdx.x * 32 + (t >> 3);
    int lane = t & 7;                // 16B chunk within each 128B half
    float acc[16];
    {
        uint4 s0 = *(const uint4*)(hS + (size_t)node * 128 + lane * 8);
        uint4 s1 = *(const uint4*)(hS + (size_t)node * 128 + 64 + lane * 8);
        acc[0] = bf2f(s0.x & 0xffff);  acc[1] = bf2f(s0.x >> 16);
        acc[2] = bf2f(s0.y & 0xffff);  acc[3] = bf2f(s0.y >> 16);
        acc[4] = bf2f(s0.z & 0xffff);  acc[5] = bf2f(s0.z >> 16);
        acc[6] = bf2f(s0.w & 0xffff);  acc[7] = bf2f(s0.w >> 16);
        acc[8] = bf2f(s1.x & 0xffff);  acc[9] = bf2f(s1.x >> 16);
        acc[10] = bf2f(s1.y & 0xffff); acc[11] = bf2f(s1.y >> 16);
        acc[12] = bf2f(s1.z & 0xffff); acc[13] = bf2f(s1.z >> 16);
        acc[14] = bf2f(s1.w & 0xffff); acc[15] = bf2f(s1.w >> 16);
        const float* bs0 = bsum + lane * 8;
        const float* bs1 = bsum + 64 + lane * 8;
#pragma unroll
        for (int j = 0; j < 8; ++j) { acc[j] += bs0[j]; acc[8 + j] += bs1[j]; }
    }
#pragma unroll 1
    for (int rel = 0; rel < RELS; ++rel) {
        const int* __restrict__ rp = rowptr + rel * (NN + 1);
        const int* __restrict__ cl = col + (size_t)rel * NE;
        const __hip_bfloat16* __restrict__ ys = Y + rel * 128 + lane * 8;
        int s = rp[node], e = rp[node + 1];
        float a[16] = {};
        int k = s;
        for (; k + 2 <= e; k += 2) {
            int i0 = cl[k], i1 = cl[k + 1];
            uint4 u0 = *(const uint4*)(ys + (size_t)i0 * 512);
            uint4 u1 = *(const uint4*)(ys + (size_t)i0 * 512 + 64);
            uint4 u2 = *(const uint4*)(ys + (size_t)i1 * 512);
            uint4 u3 = *(const uint4*)(ys + (size_t)i1 * 512 + 64);
            a[0]  += bf2f(u0.x & 0xffff) + bf2f(u2.x & 0xffff);
            a[1]  += bf2f(u0.x >> 16)    + bf2f(u2.x >> 16);
            a[2]  += bf2f(u0.y & 0xffff) + bf2f(u2.y & 0xffff);
            a[3]  += bf2f(u0.y >> 16)    + bf2f(u2.y >> 16);
            a[4]  += bf2f(u0.z & 0xffff) + bf2f(u2.z & 0xffff);
            a[5]  += bf2f(u0.z >> 16)    + bf2f(u2.z >> 16);
            a[6]  += bf2f(u0.w & 0xffff) + bf2f(u2.w & 0xffff);
            a[7]  += bf2f(u0.w >> 16)    + bf2f(u2.w >> 16);
            a[8]  += bf2f(u1.x & 0xffff) + bf2f(u3.x & 0xffff);
            a[9]  += bf2f(u1.x >> 16)    + bf2f(u3.x >> 16);
            a[10] += bf2f(u1.y & 0xffff) + bf2f(u3.y & 0xffff);
            a[11] += bf2f(u1.y >> 16)    + bf2f(u3.y >> 16);
            a[12] += bf2f(u1.z & 0xffff) + bf2f(u3.z & 0xffff);
            a[13] += bf2f(u1.z >> 16)    + bf2f(u3.z >> 16);
            a[14] += bf2f(u1.w & 0xffff) + bf2f(u3.w & 0xffff);
            a[15] += bf2f(u1.w >> 16)    + bf2f(u3.w >> 16);
        }
        if (k < e) {
            int i0 = cl[k];
            uint4 u0 = *(const uint4*)(ys + (size_t)i0 * 512);
            uint4 u1 = *(const uint4*)(ys + (size_t)i0 * 512 + 64);
            a[0]  += bf2f(u0.x & 0xffff); a[1]  += bf2f(u0.x >> 16);
            a[2]  += bf2f(u0.y & 0xffff); a[3]  += bf2f(u0.y >> 16);
            a[4]  += bf2f(u0.z & 0xffff); a[5]  += bf2f(u0.z >> 16);
            a[6]  += bf2f(u0.w & 0xffff); a[7]  += bf2f(u0.w >> 16);
            a[8]  += bf2f(u1.x & 0xffff); a[9]  += bf2f(u1.x >> 16);
            a[10] += bf2f(u1.y & 0xffff); a[11] += bf2f(u1.y >> 16);
            a[12] += bf2f(u1.z & 0xffff); a[13] += bf2f(u1.z >> 16);
            a[14] += bf2f(u1.w & 0xffff); a[15] += bf2f(u1.w >> 16);
        }
        float sc = (e > s) ? 1.0f / (float)(e - s) : 0.0f;
#pragma unroll
        for (int j = 0; j < 16; ++j) acc[j] += a[j] * sc;
    }
    uint4 o0, o1;
    float v[16];
#pragma unroll
    for (int j = 0; j < 16; ++j) v[j] = fmaxf(acc[j] * 0.25f, 0.f);
    o0.x = f2bfbits(v[0])  | ((unsigned)f2bfbits(v[1])  << 16);
    o0.y = f2bfbits(v[2])  | ((unsigned)f2bfbits(v[3])  << 16);
    o0.z = f2bfbits(v[4])  | ((unsigned)f2bfbits(v[5])  << 16);
    o0.w = f2bfbits(v[6])  | ((unsigned)f2bfbits(v[7])  << 16);
    o1.x = f2bfbits(v[8])  | ((unsigned)f2bfbits(v[9])  << 16);
    o1.y = f2bfbits(v[10]) | ((unsigned)f2bfbits(v[11]) << 16);
    o1.z = f2bfbits(v[12]) | ((unsigned)f2bfbits(v[13]) << 16);
    o1.w = f2bfbits(v[14]) | ((unsigned)f2bfbits(v[15]) << 16);
    *(uint4*)(hS + (size_t)node * 128 + lane * 8) = o0;
    *(uint4*)(hS + (size_t)node * 128 + 64 + lane * 8) = o1;
}

// ---------------- final linear: out[M,16] = h[M,128] @ W[128,16] + b ----------------

__global__ void final_linear_kernel(const __hip_bfloat16* __restrict__ h,
                                    const float* __restrict__ W,
                                    const float* __restrict__ bias, float* __restrict__ out) {
    __shared__ float Ws[128 * 16];
    __shared__ float Hs[16 * 132];
    int tid = threadIdx.x;
    int node0 = blockIdx.x * 16;
    for (int i = tid; i < 2048; i += 256) Ws[i] = W[i];
    {
        int g = tid >> 4, c = tid & 15;
        int node = node0 + g;
        float f[8] = {};
        if (node < NN) {
            uint4 v = *(const uint4*)(h + (size_t)node * 128 + c * 8);
            f[0] = bf2f(v.x & 0xffff); f[1] = bf2f(v.x >> 16);
            f[2] = bf2f(v.y & 0xffff); f[3] = bf2f(v.y >> 16);
            f[4] = bf2f(v.z & 0xffff); f[5] = bf2f(v.z >> 16);
            f[6] = bf2f(v.w & 0xffff); f[7] = bf2f(v.w >> 16);
        }
#pragma unroll
        for (int j = 0; j < 8; ++j) Hs[g * 132 + c * 8 + j] = f[j];
    }
    __syncthreads();
    int g = tid >> 4;
    int c = tid & 15;
    int node = node0 + g;
    if (node >= NN) return;
    float acc = bias[c];
#pragma unroll 8
    for (int k = 0; k < 128; ++k) acc += Hs[g * 132 + k] * Ws[k * 16 + c];
    out[node * NCLS + c] = acc;
}

// ---------------- launch ----------------

extern "C" void kernel_launch(void* const* d_in, const int* in_sizes, int n_in,
                              void* d_out, int out_size, void* d_ws, size_t ws_size,
                              hipStream_t stream) {
    const float* x     = (const float*)d_in[0];
    const int*   e0    = (const int*)d_in[1];
    const int*   e1    = (const int*)d_in[2];
    const int*   e2    = (const int*)d_in[3];
    const int*   e3    = (const int*)d_in[4];
    const float* W_nbr = (const float*)d_in[5];
    const float* b_nbr = (const float*)d_in[6];
    const float* W_root= (const float*)d_in[7];
    const float* lin_w = (const float*)d_in[8];
    const float* lin_b = (const float*)d_in[9];
    float* out = (float*)d_out;

    // workspace bump allocator (256B aligned)
    char* p = (char*)d_ws;
    auto alloc = [&](size_t bytes) -> void* {
        void* q = (void*)p;
        p += (bytes + 255) & ~(size_t)255;
        return q;
    };
    int*   counts = (int*)alloc((size_t)RELS * NN * 4);
    int*   rowptr = (int*)alloc((size_t)RELS * (NN + 1) * 4);
    int*   col    = (int*)alloc((size_t)RELS * NE * 4);
    int*   bsums  = (int*)alloc((size_t)RELS * 128 * 4);
    float* bsum   = (float*)alloc((size_t)2 * 128 * 4);
    __hip_bfloat16* BT = (__hip_bfloat16*)alloc((size_t)2 * 640 * 128 * 2);
    __hip_bfloat16* Y  = (__hip_bfloat16*)alloc((size_t)NN * 512 * 2);   // 102.4 MB
    __hip_bfloat16* hA = (__hip_bfloat16*)alloc((size_t)NN * 128 * 2);   // h0 / layer2 S+out
    __hip_bfloat16* hB = (__hip_bfloat16*)alloc((size_t)NN * 128 * 2);   // layer1 S+out

    const int eblocks = (NE + 255) / 256;

    // CSR build (shared by both layers)
    hipMemsetAsync(counts, 0, (size_t)RELS * NN * 4, stream);
    hist_kernel<<<dim3(eblocks, RELS), 256, 0, stream>>>(e0, e1, e2, e3, counts);
    scanA_kernel<<<dim3(NCHUNK, RELS), SCAN_B, 0, stream>>>(counts, bsums);
    scanB_kernel<<<1, 64, 0, stream>>>(bsums, rowptr);
    scanC_kernel<<<dim3(NCHUNK, RELS), SCAN_B, 0, stream>>>(counts, bsums, rowptr);
    hipMemsetAsync(counts, 0, (size_t)RELS * NN * 4, stream);
    fill_kernel<<<dim3(eblocks, RELS), 256, 0, stream>>>(e0, e1, e2, e3, rowptr, counts, col);

    // weights -> bf16 transposed (+ root-sum fold + bias sum)
    wconv_kernel<<<(2 * 640 * 128 + 256 + 255) / 256, 256, 0, stream>>>(
        W_nbr, W_root, b_nbr, BT, bsum);

    // x -> bf16 compact hA
    x2bf_kernel<<<(NN * 128 / 8 + 255) / 256, 256, 0, stream>>>(x, hA);

    const int rblocks = (NN + 63) / 64;   // 1563
    const int nblocks = NN / 32;          // 3125, exact

    // layer 1: hA -> (Y, hB=S) -> hB = h1
    dense_gemm_kernel<<<dim3(rblocks, 5), 256, 0, stream>>>(hA, Y, hB, BT, NN);
    gather_finish_kernel<<<nblocks, 256, 0, stream>>>(rowptr, col, Y, hB, bsum);
    // layer 2: hB -> (Y, hA=S) -> hA = h2
    dense_gemm_kernel<<<dim3(rblocks, 5), 256, 0, stream>>>(hB, Y, hA, BT + (size_t)640 * 128, NN);
    gather_finish_kernel<<<nblocks, 256, 0, stream>>>(rowptr, col, Y, hA, bsum + 128);

    final_linear_kernel<<<(NN + 15) / 16, 256, 0, stream>>>(hA, lin_w, lin_b, out);
}

// Round 11
// 619.117 us; speedup vs baseline: 1.1390x; 1.1390x over previous
//
#include <hip/hip_runtime.h>
#include <hip/hip_bf16.h>

// Problem constants (match reference)
#define NN 100000
#define NE 500000
#define RELS 4
#define NCLS 16
#define SCAN_B 1024
#define NCHUNK ((NN + SCAN_B - 1) / SCAN_B)   // 98

typedef __attribute__((ext_vector_type(8))) short s16x8;
typedef __attribute__((ext_vector_type(4))) float f32x4;

__device__ __forceinline__ float bf2f(unsigned short u) {
    return __uint_as_float(((unsigned int)u) << 16);
}
__device__ __forceinline__ unsigned short f2bfbits(float f) {
    __hip_bfloat16 h = __float2bfloat16(f);
    return *reinterpret_cast<unsigned short*>(&h);
}

// ---------------- CSR build ----------------

__global__ void hist_kernel(const int* __restrict__ e0, const int* __restrict__ e1,
                            const int* __restrict__ e2, const int* __restrict__ e3,
                            int* __restrict__ counts) {
    int i = blockIdx.x * 256 + threadIdx.x;
    int rel = blockIdx.y;
    if (i >= NE) return;
    const int* ep = (rel == 0) ? e0 : (rel == 1) ? e1 : (rel == 2) ? e2 : e3;
    int d = ep[NE + i];              // dst row
    atomicAdd(&counts[rel * NN + d], 1);
}

__global__ void scanA_kernel(const int* __restrict__ counts, int* __restrict__ bsums) {
    int rel = blockIdx.y, chunk = blockIdx.x;
    int i = chunk * SCAN_B + threadIdx.x;
    __shared__ int s[SCAN_B];
    int v = (i < NN) ? counts[rel * NN + i] : 0;
    s[threadIdx.x] = v;
    __syncthreads();
    for (int off = SCAN_B / 2; off > 0; off >>= 1) {
        if (threadIdx.x < off) s[threadIdx.x] += s[threadIdx.x + off];
        __syncthreads();
    }
    if (threadIdx.x == 0) bsums[rel * 128 + chunk] = s[0];
}

__global__ void scanB_kernel(int* __restrict__ bsums, int* __restrict__ rowptr) {
    int r = threadIdx.x;
    if (r < RELS) {
        int acc = 0;
        for (int c = 0; c < NCHUNK; ++c) {
            int v = bsums[r * 128 + c];
            bsums[r * 128 + c] = acc;
            acc += v;
        }
        rowptr[r * (NN + 1) + NN] = acc;   // == NE
    }
}

__global__ void scanC_kernel(const int* __restrict__ counts, const int* __restrict__ bsums,
                             int* __restrict__ rowptr) {
    int rel = blockIdx.y, chunk = blockIdx.x;
    int i = chunk * SCAN_B + threadIdx.x;
    __shared__ int s[SCAN_B];
    int v = (i < NN) ? counts[rel * NN + i] : 0;
    s[threadIdx.x] = v;
    __syncthreads();
    for (int off = 1; off < SCAN_B; off <<= 1) {
        int add = (threadIdx.x >= (unsigned)off) ? s[threadIdx.x - off] : 0;
        __syncthreads();
        s[threadIdx.x] += add;
        __syncthreads();
    }
    if (i < NN)
        rowptr[rel * (NN + 1) + i] = bsums[rel * 128 + chunk] + s[threadIdx.x] - v;
}

__global__ void fill_kernel(const int* __restrict__ e0, const int* __restrict__ e1,
                            const int* __restrict__ e2, const int* __restrict__ e3,
                            const int* __restrict__ rowptr, int* __restrict__ cursor,
                            int* __restrict__ col) {
    int i = blockIdx.x * 256 + threadIdx.x;
    int rel = blockIdx.y;
    if (i >= NE) return;
    const int* ep = (rel == 0) ? e0 : (rel == 1) ? e1 : (rel == 2) ? e2 : e3;
    int src = ep[i];
    int dst = ep[NE + i];
    int p = atomicAdd(&cursor[rel * NN + dst], 1);
    col[rel * NE + rowptr[rel * (NN + 1) + dst] + p] = src;
}

// ---------------- weight conversion ----------------
// BT[l][n][k] (bf16, k contiguous, n = output col 0..639):
//   n<512  -> W_nbr[l][n>>7][k][n&127]
//   n>=512 -> sum_r W_root[l][r][k][n-512]
// bsum[l][c] = sum_r b_nbr[l][r][c]  (fp32)

__global__ void wconv_kernel(const float* __restrict__ Wn, const float* __restrict__ Wr,
                             const float* __restrict__ bn, __hip_bfloat16* __restrict__ BT,
                             float* __restrict__ bsum) {
    int idx = blockIdx.x * 256 + threadIdx.x;
    if (idx < 2 * 640 * 128) {
        int l = (idx >= 640 * 128) ? 1 : 0;
        int rem = idx - l * 640 * 128;
        int n = rem >> 7;
        int k = rem & 127;
        float v;
        if (n < 512) {
            v = Wn[(((size_t)l * RELS + (n >> 7)) * 128 + k) * 128 + (n & 127)];
        } else {
            v = 0.f;
            for (int r = 0; r < RELS; ++r)
                v += Wr[(((size_t)l * RELS + r) * 128 + k) * 128 + (n - 512)];
        }
        BT[((size_t)l * 640 + n) * 128 + k] = __float2bfloat16(v);
    } else if (idx < 2 * 640 * 128 + 256) {
        int i = idx - 2 * 640 * 128;
        int l = i >> 7, c = i & 127;
        float a = 0.f;
        for (int r = 0; r < RELS; ++r) a += bn[((size_t)l * RELS + r) * 128 + c];
        bsum[i] = a;
    }
}

// ---------------- dense GEMM: [Y | S] = A @ BTl^T ----------------
// A = x (fp32, layer 1) or h (bf16, layer 2). Y stored RELATION-MAJOR
// [rel][N][128] (contiguous 256B row writes per col-tile; gather reads a
// 25.6 MB slab per relation). hS = root-sum slice. Raw output (no bias/relu).
// BM=64 rows/block, in-block loop over 5 col-tiles (A LDS-resident, loaded
// once). K=128 in 2 chunks of 64. 4 waves (2x2), wave 32x64 via 2x4
// mfma_f32_16x16x32_bf16. LDS 32 KB (A 16K + B 16K; C stages into dead B)
// -> 5 blocks/CU.

template <bool FP32A>
__global__ __launch_bounds__(256, 5) void dense_gemm_kernel(
    const void* __restrict__ Ain, __hip_bfloat16* __restrict__ Y,
    __hip_bfloat16* __restrict__ hS, const __hip_bfloat16* __restrict__ BTl, int M) {
    __shared__ uint4 smem4[2048];            // 32 KB
    char* AsB = (char*)smem4;                // [64 rows][128 k] bf16, swizzled
    char* BsB = (char*)smem4 + 16384;        // [128 n][64 k] per chunk; C reuses
    int t = threadIdx.x;
    int l = t & 63;
    int wave = t >> 6;
    int wm = wave >> 1, wn = wave & 1;
    int row0 = blockIdx.x * 64;

    int bn_ = t >> 1;                // B stage: n row 0..127
    int bj = t & 1;                  // B stage: 32-elem half
    int lrow = l & 15;               // MFMA fragment row/col within 16
    int lkg = l >> 4;                // MFMA k-group 0..3

    // ---- stage A tile: 64 rows x 256B(bf16); thread owns row t>>2, part t&3 ----
    {
        int row = t >> 2, part = t & 3;
        int grow = row0 + row;
        uint4 v[4] = {};
        if (grow < M) {
            if (FP32A) {
                const float* gx = (const float*)Ain + (size_t)grow * 128 + part * 32;
#pragma unroll
                for (int j = 0; j < 4; ++j) {
                    float4 f0 = *(const float4*)(gx + j * 8);
                    float4 f1 = *(const float4*)(gx + j * 8 + 4);
                    v[j].x = f2bfbits(f0.x) | ((unsigned)f2bfbits(f0.y) << 16);
                    v[j].y = f2bfbits(f0.z) | ((unsigned)f2bfbits(f0.w) << 16);
                    v[j].z = f2bfbits(f1.x) | ((unsigned)f2bfbits(f1.y) << 16);
                    v[j].w = f2bfbits(f1.z) | ((unsigned)f2bfbits(f1.w) << 16);
                }
            } else {
                const __hip_bfloat16* gh =
                    (const __hip_bfloat16*)Ain + (size_t)grow * 128 + part * 32;
#pragma unroll
                for (int j = 0; j < 4; ++j) v[j] = *(const uint4*)(gh + j * 8);
            }
        }
#pragma unroll
        for (int j = 0; j < 4; ++j) {
            int q = part * 4 + j;
            *(uint4*)(AsB + row * 256 + ((q ^ (row & 7)) << 4)) = v[j];
        }
    }

    uint4 breg[4];
    {   // preload B chunk 0 (ct=0, c=0)
        const __hip_bfloat16* gb = BTl + (size_t)bn_ * 128 + bj * 32;
#pragma unroll
        for (int j = 0; j < 4; ++j) breg[j] = *(const uint4*)(gb + j * 8);
    }

    f32x4 acc[2][4];
#pragma unroll
    for (int i = 0; i < 2; ++i)
#pragma unroll
        for (int j = 0; j < 4; ++j) acc[i][j] = (f32x4){0.f, 0.f, 0.f, 0.f};

    for (int ct = 0; ct < 5; ++ct) {
        for (int c = 0; c < 2; ++c) {
            __syncthreads();         // prior BsB readers (MFMA / C-store) done; A visible
#pragma unroll
            for (int j = 0; j < 4; ++j) {
                int q = bj * 4 + j;
                *(uint4*)(BsB + bn_ * 128 + ((q ^ (bn_ & 7)) << 4)) = breg[j];
            }
            int g10 = ct * 2 + c + 1;
            if (g10 < 10) {          // prefetch next B chunk under MFMA
                int ctn = g10 >> 1, cn = g10 & 1;
                const __hip_bfloat16* gb =
                    BTl + ((size_t)(ctn * 128 + bn_)) * 128 + cn * 64 + bj * 32;
#pragma unroll
                for (int j = 0; j < 4; ++j) breg[j] = *(const uint4*)(gb + j * 8);
            }
            __syncthreads();
#pragma unroll
            for (int kk = 0; kk < 2; ++kk) {
                s16x8 af[2], bfr[4];
                int qa = c * 8 + kk * 4 + lkg;
                int qb = kk * 4 + lkg;
#pragma unroll
                for (int mi = 0; mi < 2; ++mi) {
                    int row = wm * 32 + mi * 16 + lrow;
                    af[mi] = *(const s16x8*)(AsB + row * 256 + ((qa ^ (row & 7)) << 4));
                }
#pragma unroll
                for (int ni = 0; ni < 4; ++ni) {
                    int nrow = wn * 64 + ni * 16 + lrow;
                    bfr[ni] = *(const s16x8*)(BsB + nrow * 128 + ((qb ^ (nrow & 7)) << 4));
                }
#pragma unroll
                for (int mi = 0; mi < 2; ++mi)
#pragma unroll
                    for (int ni = 0; ni < 4; ++ni)
                        acc[mi][ni] = __builtin_amdgcn_mfma_f32_16x16x32_bf16(
                            af[mi], bfr[ni], acc[mi][ni], 0, 0, 0);
            }
        }
        __syncthreads();             // MFMA reads of BsB done; stage C into it
        {
            int cr = l >> 4;
            int cc = l & 15;
#pragma unroll
            for (int ni = 0; ni < 4; ++ni) {
                int colg = wn * 64 + ni * 16 + cc;
                int q = colg >> 3;
                int cb = (colg & 7) * 2;
#pragma unroll
                for (int mi = 0; mi < 2; ++mi) {
#pragma unroll
                    for (int r = 0; r < 4; ++r) {
                        int row = wm * 32 + mi * 16 + cr * 4 + r;
                        int byte = row * 256 + ((q ^ (row & 15)) << 4) + cb;
                        *(unsigned short*)(BsB + byte) = f2bfbits(acc[mi][ni][r]);
                    }
                }
            }
#pragma unroll
            for (int mi = 0; mi < 2; ++mi)
#pragma unroll
                for (int ni = 0; ni < 4; ++ni) acc[mi][ni] = (f32x4){0.f, 0.f, 0.f, 0.f};
        }
        __syncthreads();
        {   // contiguous 64B stores into relation-major slab (or hS for ct==4)
            int row = t >> 2;
            int part = t & 3;
            int grow = row0 + row;
            if (grow < M) {
                __hip_bfloat16* dst = (ct < 4)
                    ? (Y + ((size_t)ct * NN + grow) * 128 + part * 32)
                    : (hS + (size_t)grow * 128 + part * 32);
#pragma unroll
                for (int j = 0; j < 4; ++j) {
                    int q = part * 4 + j;
                    uint4 v = *(const uint4*)(BsB + row * 256 + ((q ^ (row & 15)) << 4));
                    *(uint4*)(dst + j * 8) = v;
                }
            }
        }
        // next ct's first chunk-sync protects BsB rewrite after these LDS reads
    }
}

// ---------------- gather-finish: h = relu(0.25*(sum_r mean_r(Y_r) + S + bias)) ----------------
// Y is relation-major [rel][N][128]. In-place over hS. 8 lanes x 32B per node
// (2x16B loads per edge-visit), 32 nodes per 256-thread block, unroll-2 edges.
// No LDS, no barriers -> max TLP for gather latency.

__global__ void gather_finish_kernel(const int* __restrict__ rowptr,
                                     const int* __restrict__ col,
                                     const __hip_bfloat16* __restrict__ Y,
                                     __hip_bfloat16* __restrict__ hS,
                                     const float* __restrict__ bsum) {
    int t = threadIdx.x;
    int node = blockIdx.x * 32 + (t >> 3);
    int lane = t & 7;                // 16B chunk within each 128B half
    float acc[16];
    {
        uint4 s0 = *(const uint4*)(hS + (size_t)node * 128 + lane * 8);
        uint4 s1 = *(const uint4*)(hS + (size_t)node * 128 + 64 + lane * 8);
        acc[0] = bf2f(s0.x & 0xffff);  acc[1] = bf2f(s0.x >> 16);
        acc[2] = bf2f(s0.y & 0xffff);  acc[3] = bf2f(s0.y >> 16);
        acc[4] = bf2f(s0.z & 0xffff);  acc[5] = bf2f(s0.z >> 16);
        acc[6] = bf2f(s0.w & 0xffff);  acc[7] = bf2f(s0.w >> 16);
        acc[8] = bf2f(s1.x & 0xffff);  acc[9] = bf2f(s1.x >> 16);
        acc[10] = bf2f(s1.y & 0xffff); acc[11] = bf2f(s1.y >> 16);
        acc[12] = bf2f(s1.z & 0xffff); acc[13] = bf2f(s1.z >> 16);
        acc[14] = bf2f(s1.w & 0xffff); acc[15] = bf2f(s1.w >> 16);
        const float* bs0 = bsum + lane * 8;
        const float* bs1 = bsum + 64 + lane * 8;
#pragma unroll
        for (int j = 0; j < 8; ++j) { acc[j] += bs0[j]; acc[8 + j] += bs1[j]; }
    }
#pragma unroll 1
    for (int rel = 0; rel < RELS; ++rel) {
        const int* __restrict__ rp = rowptr + rel * (NN + 1);
        const int* __restrict__ cl = col + (size_t)rel * NE;
        const __hip_bfloat16* __restrict__ ys = Y + (size_t)rel * NN * 128 + lane * 8;
        int s = rp[node], e = rp[node + 1];
        float a[16] = {};
        int k = s;
        for (; k + 2 <= e; k += 2) {
            int i0 = cl[k], i1 = cl[k + 1];
            uint4 u0 = *(const uint4*)(ys + (size_t)i0 * 128);
            uint4 u1 = *(const uint4*)(ys + (size_t)i0 * 128 + 64);
            uint4 u2 = *(const uint4*)(ys + (size_t)i1 * 128);
            uint4 u3 = *(const uint4*)(ys + (size_t)i1 * 128 + 64);
            a[0]  += bf2f(u0.x & 0xffff) + bf2f(u2.x & 0xffff);
            a[1]  += bf2f(u0.x >> 16)    + bf2f(u2.x >> 16);
            a[2]  += bf2f(u0.y & 0xffff) + bf2f(u2.y & 0xffff);
            a[3]  += bf2f(u0.y >> 16)    + bf2f(u2.y >> 16);
            a[4]  += bf2f(u0.z & 0xffff) + bf2f(u2.z & 0xffff);
            a[5]  += bf2f(u0.z >> 16)    + bf2f(u2.z >> 16);
            a[6]  += bf2f(u0.w & 0xffff) + bf2f(u2.w & 0xffff);
            a[7]  += bf2f(u0.w >> 16)    + bf2f(u2.w >> 16);
            a[8]  += bf2f(u1.x & 0xffff) + bf2f(u3.x & 0xffff);
            a[9]  += bf2f(u1.x >> 16)    + bf2f(u3.x >> 16);
            a[10] += bf2f(u1.y & 0xffff) + bf2f(u3.y & 0xffff);
            a[11] += bf2f(u1.y >> 16)    + bf2f(u3.y >> 16);
            a[12] += bf2f(u1.z & 0xffff) + bf2f(u3.z & 0xffff);
            a[13] += bf2f(u1.z >> 16)    + bf2f(u3.z >> 16);
            a[14] += bf2f(u1.w & 0xffff) + bf2f(u3.w & 0xffff);
            a[15] += bf2f(u1.w >> 16)    + bf2f(u3.w >> 16);
        }
        if (k < e) {
            int i0 = cl[k];
            uint4 u0 = *(const uint4*)(ys + (size_t)i0 * 128);
            uint4 u1 = *(const uint4*)(ys + (size_t)i0 * 128 + 64);
            a[0]  += bf2f(u0.x & 0xffff); a[1]  += bf2f(u0.x >> 16);
            a[2]  += bf2f(u0.y & 0xffff); a[3]  += bf2f(u0.y >> 16);
            a[4]  += bf2f(u0.z & 0xffff); a[5]  += bf2f(u0.z >> 16);
            a[6]  += bf2f(u0.w & 0xffff); a[7]  += bf2f(u0.w >> 16);
            a[8]  += bf2f(u1.x & 0xffff); a[9]  += bf2f(u1.x >> 16);
            a[10] += bf2f(u1.y & 0xffff); a[11] += bf2f(u1.y >> 16);
            a[12] += bf2f(u1.z & 0xffff); a[13] += bf2f(u1.z >> 16);
            a[14] += bf2f(u1.w & 0xffff); a[15] += bf2f(u1.w >> 16);
        }
        float sc = (e > s) ? 1.0f / (float)(e - s) : 0.0f;
#pragma unroll
        for (int j = 0; j < 16; ++j) acc[j] += a[j] * sc;
    }
    uint4 o0, o1;
    float v[16];
#pragma unroll
    for (int j = 0; j < 16; ++j) v[j] = fmaxf(acc[j] * 0.25f, 0.f);
    o0.x = f2bfbits(v[0])  | ((unsigned)f2bfbits(v[1])  << 16);
    o0.y = f2bfbits(v[2])  | ((unsigned)f2bfbits(v[3])  << 16);
    o0.z = f2bfbits(v[4])  | ((unsigned)f2bfbits(v[5])  << 16);
    o0.w = f2bfbits(v[6])  | ((unsigned)f2bfbits(v[7])  << 16);
    o1.x = f2bfbits(v[8])  | ((unsigned)f2bfbits(v[9])  << 16);
    o1.y = f2bfbits(v[10]) | ((unsigned)f2bfbits(v[11]) << 16);
    o1.z = f2bfbits(v[12]) | ((unsigned)f2bfbits(v[13]) << 16);
    o1.w = f2bfbits(v[14]) | ((unsigned)f2bfbits(v[15]) << 16);
    *(uint4*)(hS + (size_t)node * 128 + lane * 8) = o0;
    *(uint4*)(hS + (size_t)node * 128 + 64 + lane * 8) = o1;
}

// ---------------- final linear: out[M,16] = h[M,128] @ W[128,16] + b ----------------

__global__ void final_linear_kernel(const __hip_bfloat16* __restrict__ h,
                                    const float* __restrict__ W,
                                    const float* __restrict__ bias, float* __restrict__ out) {
    __shared__ float Ws[128 * 16];
    __shared__ float Hs[16 * 132];
    int tid = threadIdx.x;
    int node0 = blockIdx.x * 16;
    for (int i = tid; i < 2048; i += 256) Ws[i] = W[i];
    {
        int g = tid >> 4, c = tid & 15;
        int node = node0 + g;
        float f[8] = {};
        if (node < NN) {
            uint4 v = *(const uint4*)(h + (size_t)node * 128 + c * 8);
            f[0] = bf2f(v.x & 0xffff); f[1] = bf2f(v.x >> 16);
            f[2] = bf2f(v.y & 0xffff); f[3] = bf2f(v.y >> 16);
            f[4] = bf2f(v.z & 0xffff); f[5] = bf2f(v.z >> 16);
            f[6] = bf2f(v.w & 0xffff); f[7] = bf2f(v.w >> 16);
        }
#pragma unroll
        for (int j = 0; j < 8; ++j) Hs[g * 132 + c * 8 + j] = f[j];
    }
    __syncthreads();
    int g = tid >> 4;
    int c = tid & 15;
    int node = node0 + g;
    if (node >= NN) return;
    float acc = bias[c];
#pragma unroll 8
    for (int k = 0; k < 128; ++k) acc += Hs[g * 132 + k] * Ws[k * 16 + c];
    out[node * NCLS + c] = acc;
}

// ---------------- launch ----------------

extern "C" void kernel_launch(void* const* d_in, const int* in_sizes, int n_in,
                              void* d_out, int out_size, void* d_ws, size_t ws_size,
                              hipStream_t stream) {
    const float* x     = (const float*)d_in[0];
    const int*   e0    = (const int*)d_in[1];
    const int*   e1    = (const int*)d_in[2];
    const int*   e2    = (const int*)d_in[3];
    const int*   e3    = (const int*)d_in[4];
    const float* W_nbr = (const float*)d_in[5];
    const float* b_nbr = (const float*)d_in[6];
    const float* W_root= (const float*)d_in[7];
    const float* lin_w = (const float*)d_in[8];
    const float* lin_b = (const float*)d_in[9];
    float* out = (float*)d_out;

    // workspace bump allocator (256B aligned)
    char* p = (char*)d_ws;
    auto alloc = [&](size_t bytes) -> void* {
        void* q = (void*)p;
        p += (bytes + 255) & ~(size_t)255;
        return q;
    };
    int*   counts = (int*)alloc((size_t)RELS * NN * 4);
    int*   rowptr = (int*)alloc((size_t)RELS * (NN + 1) * 4);
    int*   col    = (int*)alloc((size_t)RELS * NE * 4);
    int*   bsums  = (int*)alloc((size_t)RELS * 128 * 4);
    float* bsum   = (float*)alloc((size_t)2 * 128 * 4);
    __hip_bfloat16* BT = (__hip_bfloat16*)alloc((size_t)2 * 640 * 128 * 2);
    __hip_bfloat16* Y  = (__hip_bfloat16*)alloc((size_t)RELS * NN * 128 * 2); // 102.4 MB
    __hip_bfloat16* hA = (__hip_bfloat16*)alloc((size_t)NN * 128 * 2);
    __hip_bfloat16* hB = (__hip_bfloat16*)alloc((size_t)NN * 128 * 2);

    const int eblocks = (NE + 255) / 256;

    // CSR build (shared by both layers)
    hipMemsetAsync(counts, 0, (size_t)RELS * NN * 4, stream);
    hist_kernel<<<dim3(eblocks, RELS), 256, 0, stream>>>(e0, e1, e2, e3, counts);
    scanA_kernel<<<dim3(NCHUNK, RELS), SCAN_B, 0, stream>>>(counts, bsums);
    scanB_kernel<<<1, 64, 0, stream>>>(bsums, rowptr);
    scanC_kernel<<<dim3(NCHUNK, RELS), SCAN_B, 0, stream>>>(counts, bsums, rowptr);
    hipMemsetAsync(counts, 0, (size_t)RELS * NN * 4, stream);
    fill_kernel<<<dim3(eblocks, RELS), 256, 0, stream>>>(e0, e1, e2, e3, rowptr, counts, col);

    // weights -> bf16 transposed (+ root-sum fold + bias sum)
    wconv_kernel<<<(2 * 640 * 128 + 256 + 255) / 256, 256, 0, stream>>>(
        W_nbr, W_root, b_nbr, BT, bsum);

    const int rblocks = (NN + 63) / 64;   // 1563
    const int nblocks = NN / 32;          // 3125, exact

    // layer 1: x (fp32) -> (Y, hB=S) -> hB = h1
    dense_gemm_kernel<true><<<rblocks, 256, 0, stream>>>(x, Y, hB, BT, NN);
    gather_finish_kernel<<<nblocks, 256, 0, stream>>>(rowptr, col, Y, hB, bsum);
    // layer 2: hB -> (Y, hA=S) -> hA = h2
    dense_gemm_kernel<false><<<rblocks, 256, 0, stream>>>(hB, Y, hA, BT + (size_t)640 * 128, NN);
    gather_finish_kernel<<<nblocks, 256, 0, stream>>>(rowptr, col, Y, hA, bsum + 128);

    final_linear_kernel<<<(NN + 15) / 16, 256, 0, stream>>>(hA, lin_w, lin_b, out);
}